// Round 1
// baseline (5481.906 us; speedup 1.0000x reference)
//
#include <hip/hip_runtime.h>

// ---------------------------------------------------------------------------
// PIXBA (Mamba vision encoder + MAE masking) forward, MI355X gfx950.
// Round 1: correct bf16-MFMA implementation, simple 2-barrier GEMM structure.
// ---------------------------------------------------------------------------

#define BATCH 8
#define NPATCH 196
#define LEN_KEEP 147
#define SEQ 148            // 1 + LEN_KEEP
#define DM 768
#define DI 1536
#define DTR 48
#define DST 16
#define MTOK (BATCH*SEQ)   // 1184

typedef __bf16 bf16_t;
typedef bf16_t bf16x8 __attribute__((ext_vector_type(8)));
typedef float  f32x4  __attribute__((ext_vector_type(4)));

__device__ __forceinline__ unsigned short f2bf(float f) {
    union { float f; unsigned u; } c; c.f = f;
    unsigned r = c.u + 0x7FFFu + ((c.u >> 16) & 1u);   // RNE to bf16
    return (unsigned short)(r >> 16);
}
__device__ __forceinline__ float sigmoidf_(float x) { return 1.f / (1.f + __expf(-x)); }

// ---------------------------------------------------------------------------
// im2col: pixel (8,3,224,224) -> Apatch (1568, 768), k = c*256 + i*16 + j
// ---------------------------------------------------------------------------
__global__ __launch_bounds__(256) void k_im2col(const float* __restrict__ px,
                                                float* __restrict__ Ap) {
    int idx = blockIdx.x * 256 + threadIdx.x;       // one float4 each
    if (idx >= 1568 * 192) return;
    int m = idx / 192, kq = (idx % 192) * 4;
    int b = m / NPATCH, p = m % NPATCH;
    int c = kq / 256, r = kq % 256, i = r / 16, j = r % 16;
    int y = (p / 14) * 16 + i, x = (p % 14) * 16 + j;
    float4 v = *reinterpret_cast<const float4*>(&px[((size_t)(b * 3 + c) * 224 + y) * 224 + x]);
    *reinterpret_cast<float4*>(&Ap[(size_t)m * 768 + kq]) = v;
}

// ---------------------------------------------------------------------------
// mask / argsort: brute-force stable rank per batch row (196 elems)
// ---------------------------------------------------------------------------
__global__ __launch_bounds__(256) void k_mask(const float* __restrict__ noise,
                                              int* __restrict__ ids_shuf,
                                              float* __restrict__ out_mask,
                                              float* __restrict__ out_restore) {
    __shared__ float sn[NPATCH];
    __shared__ int sshuf[NPATCH];
    int b = blockIdx.x, tid = threadIdx.x;
    if (tid < NPATCH) sn[tid] = noise[b * NPATCH + tid];
    __syncthreads();
    if (tid < NPATCH) {
        float nj = sn[tid];
        int rank = 0;
        for (int i = 0; i < NPATCH; ++i) {
            float ni = sn[i];
            rank += (ni < nj) || (ni == nj && i < tid);
        }
        out_restore[b * NPATCH + tid] = (float)rank;
        out_mask[b * NPATCH + tid] = (rank >= LEN_KEEP) ? 1.f : 0.f;
        sshuf[rank] = tid;
    }
    __syncthreads();
    if (tid < NPATCH) ids_shuf[b * NPATCH + tid] = sshuf[tid];
}

// ---------------------------------------------------------------------------
// build h: h[b,0]=cls+pos[0]; h[b,1+l]=embed[b, ids_shuf[b][l]]
// ---------------------------------------------------------------------------
__global__ __launch_bounds__(256) void k_build_h(const float* __restrict__ embed,
                                                 const int* __restrict__ ids_shuf,
                                                 const float* __restrict__ cls,
                                                 const float* __restrict__ pos,
                                                 float* __restrict__ h) {
    int blk = blockIdx.x;                // 0..1183
    int b = blk / SEQ, t = blk % SEQ, tid = threadIdx.x;
    size_t ob = (size_t)blk * DM;
    if (t == 0) {
        for (int i = tid; i < DM; i += 256) h[ob + i] = cls[i] + pos[i];
    } else {
        int j = ids_shuf[b * NPATCH + (t - 1)];
        const float* src = embed + (size_t)(b * NPATCH + j) * DM;
        for (int i = tid; i < DM; i += 256) h[ob + i] = src[i];
    }
}

// ---------------------------------------------------------------------------
// LayerNorm (eps 1e-12), 768 wide, one row per block. Safe in-place.
// ---------------------------------------------------------------------------
__global__ __launch_bounds__(256) void k_layernorm(const float* __restrict__ in,
                                                   const float* __restrict__ w,
                                                   const float* __restrict__ b,
                                                   float* __restrict__ out) {
    int row = blockIdx.x, tid = threadIdx.x;
    const float* x = in + (size_t)row * DM;
    float v0 = x[tid], v1 = x[tid + 256], v2 = x[tid + 512];
    float s = v0 + v1 + v2, q = v0 * v0 + v1 * v1 + v2 * v2;
#pragma unroll
    for (int off = 32; off; off >>= 1) {
        s += __shfl_down(s, off, 64);
        q += __shfl_down(q, off, 64);
    }
    __shared__ float ss[4], sq[4];
    int wid = tid >> 6, lane = tid & 63;
    if (lane == 0) { ss[wid] = s; sq[wid] = q; }
    __syncthreads();
    float st = ss[0] + ss[1] + ss[2] + ss[3];
    float qt = sq[0] + sq[1] + sq[2] + sq[3];
    float mu = st * (1.f / DM);
    float var = qt * (1.f / DM) - mu * mu;
    float rstd = rsqrtf(var + 1e-12f);
    float* o = out + (size_t)row * DM;
    o[tid]       = (v0 - mu) * rstd * w[tid]       + b[tid];
    o[tid + 256] = (v1 - mu) * rstd * w[tid + 256] + b[tid + 256];
    o[tid + 512] = (v2 - mu) * rstd * w[tid + 512] + b[tid + 512];
}

// ---------------------------------------------------------------------------
// Generic bf16 MFMA NT-GEMM: C[m,n] = dot(A[m,:], B[n,:]) (+epilogue)
//   A: M x K f32 (lda), B: N x K f32 (ldb), staged to LDS as bf16.
// EPI: 0=store, 1=add(+=), 2=embed (+e0[n] + e1[(1+m%196)*768+n]), 3=softplus(x+e0[n])
// ---------------------------------------------------------------------------
template <int BM, int BN, int WR, int WC, int EPI>
__global__ __launch_bounds__(256) void gemm_bf16(
    const float* __restrict__ A, int lda, int M,
    const float* __restrict__ B, int ldb,
    float* __restrict__ C, int ldc, int K,
    const float* __restrict__ e0, const float* __restrict__ e1) {
    constexpr int WM = BM / WR, WN = BN / WC;
    constexpr int FM = WM / 16, FN = WN / 16;
    constexpr int LST = 40;                  // 32 + 8 pad (ushort) -> 2-way max
    __shared__ unsigned short lsA[BM][LST];
    __shared__ unsigned short lsB[BN][LST];

    const int tid = threadIdx.x;
    const int m0 = blockIdx.x * BM;
    const int n0 = blockIdx.y * BN;
    const int lane = tid & 63, wid = tid >> 6;
    const int wr = wid / WC, wc = wid % WC;
    const int lr = lane & 15, lg = lane >> 4;

    f32x4 acc[FM][FN] = {};

    constexpr int AE = BM / 8;               // k-elems per thread (A)
    constexpr int ATPR = 32 / AE;
    const int ar = tid / ATPR, akc = (tid % ATPR) * AE;
    constexpr int BE = BN / 8;
    constexpr int BTPR = 32 / BE;
    const int br = tid / BTPR, bkc = (tid % BTPR) * BE;

    const int arow = min(m0 + ar, M - 1);
    const float* Ap = A + (size_t)arow * lda;
    const float* Bp = B + (size_t)(n0 + br) * ldb;

    for (int k0 = 0; k0 < K; k0 += 32) {
#pragma unroll
        for (int f = 0; f < AE / 4; ++f) {
            int kk = k0 + akc + 4 * f;
            float4 v = make_float4(0.f, 0.f, 0.f, 0.f);
            if (kk < K) v = *reinterpret_cast<const float4*>(Ap + kk);
            ushort4 w4 = { f2bf(v.x), f2bf(v.y), f2bf(v.z), f2bf(v.w) };
            *reinterpret_cast<ushort4*>(&lsA[ar][akc + 4 * f]) = w4;
        }
#pragma unroll
        for (int f = 0; f < BE / 4; ++f) {
            int kk = k0 + bkc + 4 * f;
            float4 v = make_float4(0.f, 0.f, 0.f, 0.f);
            if (kk < K) v = *reinterpret_cast<const float4*>(Bp + kk);
            ushort4 w4 = { f2bf(v.x), f2bf(v.y), f2bf(v.z), f2bf(v.w) };
            *reinterpret_cast<ushort4*>(&lsB[br][bkc + 4 * f]) = w4;
        }
        __syncthreads();
        bf16x8 av[FM], bv[FN];
#pragma unroll
        for (int i = 0; i < FM; ++i)
            av[i] = *reinterpret_cast<const bf16x8*>(&lsA[wr * WM + i * 16 + lr][lg * 8]);
#pragma unroll
        for (int j = 0; j < FN; ++j)
            bv[j] = *reinterpret_cast<const bf16x8*>(&lsB[wc * WN + j * 16 + lr][lg * 8]);
#pragma unroll
        for (int i = 0; i < FM; ++i)
#pragma unroll
            for (int j = 0; j < FN; ++j)
                acc[i][j] = __builtin_amdgcn_mfma_f32_16x16x32_bf16(av[i], bv[j], acc[i][j], 0, 0, 0);
        __syncthreads();
    }
#pragma unroll
    for (int i = 0; i < FM; ++i) {
#pragma unroll
        for (int r = 0; r < 4; ++r) {
            int m = m0 + wr * WM + i * 16 + lg * 4 + r;
            if (m >= M) continue;
#pragma unroll
            for (int j = 0; j < FN; ++j) {
                int n = n0 + wc * WN + j * 16 + lr;
                float v = acc[i][j][r];
                size_t idx = (size_t)m * ldc + n;
                if (EPI == 0) {
                    C[idx] = v;
                } else if (EPI == 1) {
                    C[idx] += v;
                } else if (EPI == 2) {
                    C[idx] = v + e0[n] + e1[(size_t)(1 + (m % NPATCH)) * DM + n];
                } else {  // softplus(v + bias)
                    float x = v + e0[n];
                    C[idx] = (x > 20.f) ? x : log1pf(__expf(x));
                }
            }
        }
    }
}

// ---------------------------------------------------------------------------
// G2: fused causal depthwise conv(4)+silu -> xc  AND  xdbl = xc @ W_x^T (N=80)
// BM=64 tokens, 4 waves (16 rows each, 5 n-frags), K = D_INNER = 1536.
// ---------------------------------------------------------------------------
__global__ __launch_bounds__(256) void k_g2_conv(
    const float* __restrict__ xz,   // [1184][3072] (xs = cols 0..1535)
    const float* __restrict__ Wx,   // [80][1536]
    const float* __restrict__ cw,   // [1536][4]
    const float* __restrict__ cb,   // [1536]
    float* __restrict__ xc,         // [1184][1536]
    float* __restrict__ xdbl) {     // [1184][80]
    __shared__ unsigned short lsA[64][40];
    __shared__ unsigned short lsB[80][40];
    __shared__ float scw[DI * 4];
    const int tid = threadIdx.x;
    const int m0 = blockIdx.x * 64;
    for (int i = tid; i < DI; i += 256) {
        float4 v = *reinterpret_cast<const float4*>(&cw[i * 4]);
        *reinterpret_cast<float4*>(&scw[i * 4]) = v;
    }
    __syncthreads();

    const int lane = tid & 63, wid = tid >> 6;
    const int lr = lane & 15, lg = lane >> 4;
    f32x4 acc[5] = {};

    const int tt = tid >> 2;
    const int kc0 = (tid & 3) * 8;
    const int m = m0 + tt;
    const int mc = min(m, MTOK - 1);
    const int b = mc / SEQ, ti = mc % SEQ;

    for (int k0 = 0; k0 < DI; k0 += 32) {
        // ---- stage A = silu(conv1d(xs)) ----
#pragma unroll
        for (int g4 = 0; g4 < 8; g4 += 4) {
            int d0 = k0 + kc0 + g4;
            float4 a4 = *reinterpret_cast<const float4*>(&cb[d0]);
#pragma unroll
            for (int j = 0; j < 4; ++j) {
                int tj = ti - 3 + j;
                if (tj >= 0) {
                    float4 xv = *reinterpret_cast<const float4*>(
                        &xz[(size_t)(b * SEQ + tj) * (2 * DI) + d0]);
                    a4.x += xv.x * scw[(d0 + 0) * 4 + j];
                    a4.y += xv.y * scw[(d0 + 1) * 4 + j];
                    a4.z += xv.z * scw[(d0 + 2) * 4 + j];
                    a4.w += xv.w * scw[(d0 + 3) * 4 + j];
                }
            }
            a4.x *= sigmoidf_(a4.x);
            a4.y *= sigmoidf_(a4.y);
            a4.z *= sigmoidf_(a4.z);
            a4.w *= sigmoidf_(a4.w);
            ushort4 w4 = { f2bf(a4.x), f2bf(a4.y), f2bf(a4.z), f2bf(a4.w) };
            *reinterpret_cast<ushort4*>(&lsA[tt][kc0 + g4]) = w4;
            if (m < MTOK)
                *reinterpret_cast<float4*>(&xc[(size_t)m * DI + d0]) = a4;
        }
        // ---- stage B = W_x tile ----
        for (int idx = tid; idx < 640; idx += 256) {
            int rn = idx >> 3, kc = (idx & 7) * 4;
            float4 v = *reinterpret_cast<const float4*>(&Wx[(size_t)rn * DI + k0 + kc]);
            ushort4 w4 = { f2bf(v.x), f2bf(v.y), f2bf(v.z), f2bf(v.w) };
            *reinterpret_cast<ushort4*>(&lsB[rn][kc]) = w4;
        }
        __syncthreads();
        bf16x8 av = *reinterpret_cast<const bf16x8*>(&lsA[wid * 16 + lr][lg * 8]);
#pragma unroll
        for (int j = 0; j < 5; ++j) {
            bf16x8 bv = *reinterpret_cast<const bf16x8*>(&lsB[j * 16 + lr][lg * 8]);
            acc[j] = __builtin_amdgcn_mfma_f32_16x16x32_bf16(av, bv, acc[j], 0, 0, 0);
        }
        __syncthreads();
    }
#pragma unroll
    for (int j = 0; j < 5; ++j)
#pragma unroll
        for (int r = 0; r < 4; ++r) {
            int mm = m0 + wid * 16 + lg * 4 + r;
            if (mm < MTOK) xdbl[(size_t)mm * 80 + j * 16 + lr] = acc[j][r];
        }
}

// ---------------------------------------------------------------------------
// Selective scan. 4 lanes per channel d (4 state-dims each), sequential over L.
// y[b,l,d] = (sum_n h*C + xc*Dp) * silu(z)
// ---------------------------------------------------------------------------
__global__ __launch_bounds__(256) void k_scan(
    const float* __restrict__ dt,    // [1184][1536] (softplus'ed)
    const float* __restrict__ xc,    // [1184][1536]
    const float* __restrict__ xdbl,  // [1184][80]: [.,48..64)=Bm, [.,64..80)=Cm
    const float* __restrict__ xz,    // [1184][3072]: z = cols 1536..3071
    const float* __restrict__ A_log, // [1536][16] (layer slice)
    const float* __restrict__ Dp,    // [1536]
    float* __restrict__ y) {         // [1184][1536]
    int g = blockIdx.x * 256 + threadIdx.x;  // 49152 threads
    int ng = g & 3;
    int di = g >> 2;
    int b = di / DI, d = di % DI;
    float An[4], hst[4] = {0.f, 0.f, 0.f, 0.f};
#pragma unroll
    for (int n = 0; n < 4; ++n) An[n] = -__expf(A_log[d * DST + ng * 4 + n]);
    float Dv = Dp[d];
    for (int t = 0; t < SEQ; ++t) {
        size_t row = (size_t)(b * SEQ + t);
        float dtv = dt[row * DI + d];
        float xcv = xc[row * DI + d];
        float dtx = dtv * xcv;
        float4 Bm = *reinterpret_cast<const float4*>(&xdbl[row * 80 + DTR + ng * 4]);
        float4 Cm = *reinterpret_cast<const float4*>(&xdbl[row * 80 + DTR + DST + ng * 4]);
        float yp;
        float dA0 = __expf(dtv * An[0]); hst[0] = dA0 * hst[0] + dtx * Bm.x; yp  = hst[0] * Cm.x;
        float dA1 = __expf(dtv * An[1]); hst[1] = dA1 * hst[1] + dtx * Bm.y; yp += hst[1] * Cm.y;
        float dA2 = __expf(dtv * An[2]); hst[2] = dA2 * hst[2] + dtx * Bm.z; yp += hst[2] * Cm.z;
        float dA3 = __expf(dtv * An[3]); hst[3] = dA3 * hst[3] + dtx * Bm.w; yp += hst[3] * Cm.w;
        yp += __shfl_xor(yp, 1, 64);
        yp += __shfl_xor(yp, 2, 64);
        if (ng == 0) {
            float zv = xz[row * (2 * DI) + DI + d];
            float yv = yp + xcv * Dv;
            y[row * DI + d] = yv * (zv * sigmoidf_(zv));
        }
    }
}

// ---------------------------------------------------------------------------
extern "C" void kernel_launch(void* const* d_in, const int* in_sizes, int n_in,
                              void* d_out, int out_size, void* d_ws, size_t ws_size,
                              hipStream_t stream) {
    const float* pixel  = (const float*)d_in[0];
    const float* noise  = (const float*)d_in[1];
    const float* conv_w = (const float*)d_in[2];
    const float* conv_b = (const float*)d_in[3];
    const float* cls    = (const float*)d_in[4];
    const float* pos    = (const float*)d_in[5];
    const float* ln_w   = (const float*)d_in[6];
    const float* ln_b   = (const float*)d_in[7];
    const float* W_in   = (const float*)d_in[8];
    const float* c1w    = (const float*)d_in[9];
    const float* c1b    = (const float*)d_in[10];
    const float* W_x    = (const float*)d_in[11];
    const float* W_dt   = (const float*)d_in[12];
    const float* dtb    = (const float*)d_in[13];
    const float* A_log  = (const float*)d_in[14];
    const float* Dp     = (const float*)d_in[15];
    const float* W_out  = (const float*)d_in[16];
    const float* lnf_w  = (const float*)d_in[17];
    const float* lnf_b  = (const float*)d_in[18];

    float* out = (float*)d_out;
    float* h = out;                          // [1184][768]
    float* out_mask    = out + MTOK * DM;             // 909312
    float* out_restore = out + MTOK * DM + BATCH * NPATCH;

    // workspace layout (floats); Apatch aliases xz, embed aliases dt.
    float* ws   = (float*)d_ws;
    float* xln  = ws;                         // 909312
    float* xz   = ws + 909312;                // 3637248
    float* xc   = ws + 4546560;               // 1818624
    float* dt   = ws + 6365184;               // 1818624
    float* yb   = ws + 8183808;               // 1818624
    float* xdbl = ws + 10002432;              // 94720
    int*   ids  = (int*)(ws + 10097152);      // 1568 ints
    float* Apatch = xz;
    float* embed  = dt;

    // ---- setup ----
    k_im2col<<<(1568 * 192 + 255) / 256, 256, 0, stream>>>(pixel, Apatch);
    k_mask<<<BATCH, 256, 0, stream>>>(noise, ids, out_mask, out_restore);
    // patch embed GEMM: (1568x768) @ (768x768)^T, epilogue +conv_b +pos[1+p]
    gemm_bf16<64, 128, 1, 4, 2><<<dim3(25, 6), 256, 0, stream>>>(
        Apatch, 768, 1568, conv_w, 768, embed, DM, 768, conv_b, pos);
    k_build_h<<<MTOK, 256, 0, stream>>>(embed, ids, cls, pos, h);

    // ---- layers ----
    for (int l = 0; l < 12; ++l) {
        k_layernorm<<<MTOK, 256, 0, stream>>>(h, ln_w + l * DM, ln_b + l * DM, xln);
        // xz = xln @ W_in^T   (1184x768)x(3072x768)
        gemm_bf16<128, 128, 2, 2, 0><<<dim3(10, 24), 256, 0, stream>>>(
            xln, DM, MTOK, W_in + (size_t)l * 2 * DI * DM, DM, xz, 2 * DI, DM,
            nullptr, nullptr);
        // conv+silu -> xc; xdbl = xc @ W_x^T (N=80)
        k_g2_conv<<<19, 256, 0, stream>>>(
            xz, W_x + (size_t)l * (DTR + 2 * DST) * DI, c1w + l * DI * 4,
            c1b + l * DI, xc, xdbl);
        // dt = softplus(xdbl[:, :48] @ W_dt^T + dtb)   (K=48, zero-padded)
        gemm_bf16<128, 128, 2, 2, 3><<<dim3(10, 12), 256, 0, stream>>>(
            xdbl, 80, MTOK, W_dt + (size_t)l * DI * DTR, DTR, dt, DI, DTR,
            dtb + l * DI, nullptr);
        k_scan<<<192, 256, 0, stream>>>(dt, xc, xdbl, xz,
                                        A_log + (size_t)l * DI * DST, Dp + l * DI, yb);
        // h += yb @ W_out^T   (1184x1536)x(768x1536)
        gemm_bf16<64, 128, 1, 4, 1><<<dim3(19, 6), 256, 0, stream>>>(
            yb, DI, MTOK, W_out + (size_t)l * DM * DI, DI, h, DM, DI,
            nullptr, nullptr);
    }
    k_layernorm<<<MTOK, 256, 0, stream>>>(h, lnf_w, lnf_b, h);
}

// Round 2
// 5174.005 us; speedup vs baseline: 1.0595x; 1.0595x over previous
//
#include <hip/hip_runtime.h>

// ---------------------------------------------------------------------------
// PIXBA (Mamba vision encoder + MAE masking) forward, MI355X gfx950.
// Round 2: parallelize G2 (conv split out + split-K Wx GEMM), 16-lane scan.
// ---------------------------------------------------------------------------

#define BATCH 8
#define NPATCH 196
#define LEN_KEEP 147
#define SEQ 148            // 1 + LEN_KEEP
#define DM 768
#define DI 1536
#define DTR 48
#define DST 16
#define MTOK (BATCH*SEQ)   // 1184

typedef __bf16 bf16_t;
typedef bf16_t bf16x8 __attribute__((ext_vector_type(8)));
typedef float  f32x4  __attribute__((ext_vector_type(4)));

__device__ __forceinline__ unsigned short f2bf(float f) {
    union { float f; unsigned u; } c; c.f = f;
    unsigned r = c.u + 0x7FFFu + ((c.u >> 16) & 1u);   // RNE to bf16
    return (unsigned short)(r >> 16);
}
__device__ __forceinline__ float sigmoidf_(float x) { return 1.f / (1.f + __expf(-x)); }

// ---------------------------------------------------------------------------
// im2col: pixel (8,3,224,224) -> Apatch (1568, 768), k = c*256 + i*16 + j
// ---------------------------------------------------------------------------
__global__ __launch_bounds__(256) void k_im2col(const float* __restrict__ px,
                                                float* __restrict__ Ap) {
    int idx = blockIdx.x * 256 + threadIdx.x;       // one float4 each
    if (idx >= 1568 * 192) return;
    int m = idx / 192, kq = (idx % 192) * 4;
    int b = m / NPATCH, p = m % NPATCH;
    int c = kq / 256, r = kq % 256, i = r / 16, j = r % 16;
    int y = (p / 14) * 16 + i, x = (p % 14) * 16 + j;
    float4 v = *reinterpret_cast<const float4*>(&px[((size_t)(b * 3 + c) * 224 + y) * 224 + x]);
    *reinterpret_cast<float4*>(&Ap[(size_t)m * 768 + kq]) = v;
}

// ---------------------------------------------------------------------------
// mask / argsort: brute-force stable rank per batch row (196 elems)
// ---------------------------------------------------------------------------
__global__ __launch_bounds__(256) void k_mask(const float* __restrict__ noise,
                                              int* __restrict__ ids_shuf,
                                              float* __restrict__ out_mask,
                                              float* __restrict__ out_restore) {
    __shared__ float sn[NPATCH];
    __shared__ int sshuf[NPATCH];
    int b = blockIdx.x, tid = threadIdx.x;
    if (tid < NPATCH) sn[tid] = noise[b * NPATCH + tid];
    __syncthreads();
    if (tid < NPATCH) {
        float nj = sn[tid];
        int rank = 0;
        for (int i = 0; i < NPATCH; ++i) {
            float ni = sn[i];
            rank += (ni < nj) || (ni == nj && i < tid);
        }
        out_restore[b * NPATCH + tid] = (float)rank;
        out_mask[b * NPATCH + tid] = (rank >= LEN_KEEP) ? 1.f : 0.f;
        sshuf[rank] = tid;
    }
    __syncthreads();
    if (tid < NPATCH) ids_shuf[b * NPATCH + tid] = sshuf[tid];
}

// ---------------------------------------------------------------------------
// build h: h[b,0]=cls+pos[0]; h[b,1+l]=embed[b, ids_shuf[b][l]]
// ---------------------------------------------------------------------------
__global__ __launch_bounds__(256) void k_build_h(const float* __restrict__ embed,
                                                 const int* __restrict__ ids_shuf,
                                                 const float* __restrict__ cls,
                                                 const float* __restrict__ pos,
                                                 float* __restrict__ h) {
    int blk = blockIdx.x;                // 0..1183
    int b = blk / SEQ, t = blk % SEQ, tid = threadIdx.x;
    size_t ob = (size_t)blk * DM;
    if (t == 0) {
        for (int i = tid; i < DM; i += 256) h[ob + i] = cls[i] + pos[i];
    } else {
        int j = ids_shuf[b * NPATCH + (t - 1)];
        const float* src = embed + (size_t)(b * NPATCH + j) * DM;
        for (int i = tid; i < DM; i += 256) h[ob + i] = src[i];
    }
}

// ---------------------------------------------------------------------------
// LayerNorm (eps 1e-12), 768 wide, one row per block. Safe in-place.
// ---------------------------------------------------------------------------
__global__ __launch_bounds__(256) void k_layernorm(const float* __restrict__ in,
                                                   const float* __restrict__ w,
                                                   const float* __restrict__ b,
                                                   float* __restrict__ out) {
    int row = blockIdx.x, tid = threadIdx.x;
    const float* x = in + (size_t)row * DM;
    float v0 = x[tid], v1 = x[tid + 256], v2 = x[tid + 512];
    float s = v0 + v1 + v2, q = v0 * v0 + v1 * v1 + v2 * v2;
#pragma unroll
    for (int off = 32; off; off >>= 1) {
        s += __shfl_down(s, off, 64);
        q += __shfl_down(q, off, 64);
    }
    __shared__ float ss[4], sq[4];
    int wid = tid >> 6, lane = tid & 63;
    if (lane == 0) { ss[wid] = s; sq[wid] = q; }
    __syncthreads();
    float st = ss[0] + ss[1] + ss[2] + ss[3];
    float qt = sq[0] + sq[1] + sq[2] + sq[3];
    float mu = st * (1.f / DM);
    float var = qt * (1.f / DM) - mu * mu;
    float rstd = rsqrtf(var + 1e-12f);
    float* o = out + (size_t)row * DM;
    o[tid]       = (v0 - mu) * rstd * w[tid]       + b[tid];
    o[tid + 256] = (v1 - mu) * rstd * w[tid + 256] + b[tid + 256];
    o[tid + 512] = (v2 - mu) * rstd * w[tid + 512] + b[tid + 512];
}

// ---------------------------------------------------------------------------
// Generic bf16 MFMA NT-GEMM: C[m,n] = dot(A[m,kRange], B[n,kRange]) (+epilogue)
//   A: M x K f32 (lda), B: N x K f32 (ldb), staged to LDS as bf16.
//   Split-K via blockIdx.z * kChunk.
// EPI: 0=store, 1=add(+=), 2=embed (+e0[n] + e1[(1+m%196)*768+n]),
//      3=softplus(x+e0[n]), 4=atomicAdd (split-K partial)
// ---------------------------------------------------------------------------
template <int BM, int BN, int WR, int WC, int EPI>
__global__ __launch_bounds__(256) void gemm_bf16(
    const float* __restrict__ A, int lda, int M,
    const float* __restrict__ B, int ldb,
    float* __restrict__ C, int ldc, int K, int kChunk,
    const float* __restrict__ e0, const float* __restrict__ e1) {
    constexpr int WM = BM / WR, WN = BN / WC;
    constexpr int FM = WM / 16, FN = WN / 16;
    constexpr int LST = 40;                  // 32 + 8 pad (ushort)
    __shared__ unsigned short lsA[BM][LST];
    __shared__ unsigned short lsB[BN][LST];

    const int tid = threadIdx.x;
    const int m0 = blockIdx.x * BM;
    const int n0 = blockIdx.y * BN;
    const int kStart = blockIdx.z * kChunk;
    const int kEnd = min(kStart + kChunk, K);
    const int lane = tid & 63, wid = tid >> 6;
    const int wr = wid / WC, wc = wid % WC;
    const int lr = lane & 15, lg = lane >> 4;

    f32x4 acc[FM][FN] = {};

    for (int k0 = kStart; k0 < kEnd; k0 += 32) {
        // generic staging: idx -> (row, 4-elem k chunk)
        for (int idx = tid; idx < BM * 8; idx += 256) {
            int r = idx >> 3, kc = (idx & 7) * 4;
            int kk = k0 + kc;
            float4 v = make_float4(0.f, 0.f, 0.f, 0.f);
            if (kk < K) {
                int ar = min(m0 + r, M - 1);
                v = *reinterpret_cast<const float4*>(A + (size_t)ar * lda + kk);
            }
            ushort4 w4 = { f2bf(v.x), f2bf(v.y), f2bf(v.z), f2bf(v.w) };
            *reinterpret_cast<ushort4*>(&lsA[r][kc]) = w4;
        }
        for (int idx = tid; idx < BN * 8; idx += 256) {
            int r = idx >> 3, kc = (idx & 7) * 4;
            int kk = k0 + kc;
            float4 v = make_float4(0.f, 0.f, 0.f, 0.f);
            if (kk < K)
                v = *reinterpret_cast<const float4*>(B + (size_t)(n0 + r) * ldb + kk);
            ushort4 w4 = { f2bf(v.x), f2bf(v.y), f2bf(v.z), f2bf(v.w) };
            *reinterpret_cast<ushort4*>(&lsB[r][kc]) = w4;
        }
        __syncthreads();
        bf16x8 av[FM], bv[FN];
#pragma unroll
        for (int i = 0; i < FM; ++i)
            av[i] = *reinterpret_cast<const bf16x8*>(&lsA[wr * WM + i * 16 + lr][lg * 8]);
#pragma unroll
        for (int j = 0; j < FN; ++j)
            bv[j] = *reinterpret_cast<const bf16x8*>(&lsB[wc * WN + j * 16 + lr][lg * 8]);
#pragma unroll
        for (int i = 0; i < FM; ++i)
#pragma unroll
            for (int j = 0; j < FN; ++j)
                acc[i][j] = __builtin_amdgcn_mfma_f32_16x16x32_bf16(av[i], bv[j], acc[i][j], 0, 0, 0);
        __syncthreads();
    }
#pragma unroll
    for (int i = 0; i < FM; ++i) {
#pragma unroll
        for (int r = 0; r < 4; ++r) {
            int m = m0 + wr * WM + i * 16 + lg * 4 + r;
            if (m >= M) continue;
#pragma unroll
            for (int j = 0; j < FN; ++j) {
                int n = n0 + wc * WN + j * 16 + lr;
                float v = acc[i][j][r];
                size_t idx = (size_t)m * ldc + n;
                if (EPI == 0) {
                    C[idx] = v;
                } else if (EPI == 1) {
                    C[idx] += v;
                } else if (EPI == 2) {
                    C[idx] = v + e0[n] + e1[(size_t)(1 + (m % NPATCH)) * DM + n];
                } else if (EPI == 3) {
                    float x = v + e0[n];
                    C[idx] = (x > 20.f) ? x : log1pf(__expf(x));
                } else {  // 4: split-K partial
                    atomicAdd(&C[idx], v);
                }
            }
        }
    }
}

// ---------------------------------------------------------------------------
// Causal depthwise conv(4) + silu, one token row per block; also zeroes xdbl.
// Channels d = tid + 256*j (coalesced).
// ---------------------------------------------------------------------------
__global__ __launch_bounds__(256) void k_conv(
    const float* __restrict__ xz,   // [1184][3072] (xs = cols 0..1535)
    const float* __restrict__ cw,   // [1536][4]
    const float* __restrict__ cb,   // [1536]
    float* __restrict__ xc,         // [1184][1536]
    float* __restrict__ xdbl) {     // [1184][80] -> zeroed
    int row = blockIdx.x, tid = threadIdx.x;
    int ti = row % SEQ;
    const float* base = xz + (size_t)row * (2 * DI);
    if (tid < 80) xdbl[(size_t)row * 80 + tid] = 0.f;
#pragma unroll
    for (int j = 0; j < 6; ++j) {
        int d = tid + 256 * j;
        float4 w4 = *reinterpret_cast<const float4*>(&cw[d * 4]);
        float acc = cb[d];
        if (ti >= 3) acc += base[(ptrdiff_t)(-3) * (2 * DI) + d] * w4.x;
        if (ti >= 2) acc += base[(ptrdiff_t)(-2) * (2 * DI) + d] * w4.y;
        if (ti >= 1) acc += base[(ptrdiff_t)(-1) * (2 * DI) + d] * w4.z;
        acc += base[d] * w4.w;
        acc = acc * sigmoidf_(acc);
        xc[(size_t)row * DI + d] = acc;
    }
}

// ---------------------------------------------------------------------------
// Selective scan: 16 lanes per channel d (1 state each), sequential over L.
// 196608 threads = 768 blocks.
// ---------------------------------------------------------------------------
__global__ __launch_bounds__(256) void k_scan(
    const float* __restrict__ dt,    // [1184][1536] (softplus'ed)
    const float* __restrict__ xc,    // [1184][1536]
    const float* __restrict__ xdbl,  // [1184][80]: [.,48..64)=Bm, [.,64..80)=Cm
    const float* __restrict__ xz,    // [1184][3072]: z = cols 1536..3071
    const float* __restrict__ A_log, // [1536][16] (layer slice)
    const float* __restrict__ Dp,    // [1536]
    float* __restrict__ y) {         // [1184][1536]
    int g = blockIdx.x * 256 + threadIdx.x;  // 196608 threads
    int n = g & 15;
    int di = g >> 4;
    int b = di / DI, d = di % DI;
    float An = -__expf(A_log[d * DST + n]);
    float Dv = Dp[d];
    float h = 0.f;
    for (int t = 0; t < SEQ; ++t) {
        size_t row = (size_t)(b * SEQ + t);
        float dtv = dt[row * DI + d];
        float xcv = xc[row * DI + d];
        float Bn = xdbl[row * 80 + DTR + n];
        float Cn = xdbl[row * 80 + DTR + DST + n];
        h = __expf(dtv * An) * h + (dtv * xcv) * Bn;
        float yp = h * Cn;
        yp += __shfl_xor(yp, 1, 64);
        yp += __shfl_xor(yp, 2, 64);
        yp += __shfl_xor(yp, 4, 64);
        yp += __shfl_xor(yp, 8, 64);
        if (n == 0) {
            float zv = xz[row * (2 * DI) + DI + d];
            float yv = yp + xcv * Dv;
            y[row * DI + d] = yv * (zv * sigmoidf_(zv));
        }
    }
}

// ---------------------------------------------------------------------------
extern "C" void kernel_launch(void* const* d_in, const int* in_sizes, int n_in,
                              void* d_out, int out_size, void* d_ws, size_t ws_size,
                              hipStream_t stream) {
    const float* pixel  = (const float*)d_in[0];
    const float* noise  = (const float*)d_in[1];
    const float* conv_w = (const float*)d_in[2];
    const float* conv_b = (const float*)d_in[3];
    const float* cls    = (const float*)d_in[4];
    const float* pos    = (const float*)d_in[5];
    const float* ln_w   = (const float*)d_in[6];
    const float* ln_b   = (const float*)d_in[7];
    const float* W_in   = (const float*)d_in[8];
    const float* c1w    = (const float*)d_in[9];
    const float* c1b    = (const float*)d_in[10];
    const float* W_x    = (const float*)d_in[11];
    const float* W_dt   = (const float*)d_in[12];
    const float* dtb    = (const float*)d_in[13];
    const float* A_log  = (const float*)d_in[14];
    const float* Dp     = (const float*)d_in[15];
    const float* W_out  = (const float*)d_in[16];
    const float* lnf_w  = (const float*)d_in[17];
    const float* lnf_b  = (const float*)d_in[18];

    float* out = (float*)d_out;
    float* h = out;                                   // [1184][768]
    float* out_mask    = out + MTOK * DM;
    float* out_restore = out + MTOK * DM + BATCH * NPATCH;

    // workspace layout (floats); Apatch aliases xz, embed aliases dt.
    float* ws   = (float*)d_ws;
    float* xln  = ws;                         // 909312
    float* xz   = ws + 909312;                // 3637248
    float* xc   = ws + 4546560;               // 1818624
    float* dt   = ws + 6365184;               // 1818624
    float* yb   = ws + 8183808;               // 1818624
    float* xdbl = ws + 10002432;              // 94720
    int*   ids  = (int*)(ws + 10097152);      // 1568 ints
    float* Apatch = xz;
    float* embed  = dt;

    // ---- setup ----
    k_im2col<<<(1568 * 192 + 255) / 256, 256, 0, stream>>>(pixel, Apatch);
    k_mask<<<BATCH, 256, 0, stream>>>(noise, ids, out_mask, out_restore);
    gemm_bf16<64, 128, 1, 4, 2><<<dim3(25, 6, 1), 256, 0, stream>>>(
        Apatch, 768, 1568, conv_w, 768, embed, DM, 768, 768, conv_b, pos);
    k_build_h<<<MTOK, 256, 0, stream>>>(embed, ids, cls, pos, h);

    // ---- layers ----
    for (int l = 0; l < 12; ++l) {
        k_layernorm<<<MTOK, 256, 0, stream>>>(h, ln_w + l * DM, ln_b + l * DM, xln);
        // xz = xln @ W_in^T   (1184x768)x(3072x768)
        gemm_bf16<128, 128, 2, 2, 0><<<dim3(10, 24, 1), 256, 0, stream>>>(
            xln, DM, MTOK, W_in + (size_t)l * 2 * DI * DM, DM, xz, 2 * DI, DM, DM,
            nullptr, nullptr);
        // conv+silu -> xc (also zeroes xdbl)
        k_conv<<<MTOK, 256, 0, stream>>>(xz, c1w + l * DI * 4, c1b + l * DI, xc, xdbl);
        // xdbl += xc @ W_x^T  (split-K: 8 chunks of 192)
        gemm_bf16<64, 80, 4, 1, 4><<<dim3(19, 1, 8), 256, 0, stream>>>(
            xc, DI, MTOK, W_x + (size_t)l * (DTR + 2 * DST) * DI, DI,
            xdbl, 80, DI, 192, nullptr, nullptr);
        // dt = softplus(xdbl[:, :48] @ W_dt^T + dtb)
        gemm_bf16<64, 128, 1, 4, 3><<<dim3(19, 12, 1), 256, 0, stream>>>(
            xdbl, 80, MTOK, W_dt + (size_t)l * DI * DTR, DTR, dt, DI, DTR, DTR,
            dtb + l * DI, nullptr);
        k_scan<<<768, 256, 0, stream>>>(dt, xc, xdbl, xz,
                                        A_log + (size_t)l * DI * DST, Dp + l * DI, yb);
        // h += yb @ W_out^T   (1184x1536)x(768x1536)
        gemm_bf16<64, 128, 1, 4, 1><<<dim3(19, 6, 1), 256, 0, stream>>>(
            yb, DI, MTOK, W_out + (size_t)l * DM * DI, DI, h, DM, DI, DI,
            nullptr, nullptr);
    }
    k_layernorm<<<MTOK, 256, 0, stream>>>(h, lnf_w, lnf_b, h);
}

// Round 3
// 2429.181 us; speedup vs baseline: 2.2567x; 2.1299x over previous
//
#include <hip/hip_runtime.h>

// ---------------------------------------------------------------------------
// PIXBA (Mamba vision encoder + MAE masking) forward, MI355X gfx950.
// Round 3: bf16 everywhere; GEMM = global_load_lds(16B) + XOR-swizzle +
// 2-phase double-buffered pipeline; split-K for occupancy.
// ---------------------------------------------------------------------------

#define BATCH 8
#define NPATCH 196
#define LEN_KEEP 147
#define SEQ 148            // 1 + LEN_KEEP
#define DM 768
#define DI 1536
#define DTR 48
#define DST 16
#define MTOK (BATCH*SEQ)   // 1184

typedef __bf16 bf16_t;
typedef bf16_t bf16x8 __attribute__((ext_vector_type(8)));
typedef float  f32x4  __attribute__((ext_vector_type(4)));
typedef unsigned short u16;
typedef u16 u16x8 __attribute__((ext_vector_type(8)));

__device__ __forceinline__ u16 f2bf(float f) {
    union { float f; unsigned u; } c; c.f = f;
    unsigned r = c.u + 0x7FFFu + ((c.u >> 16) & 1u);   // RNE to bf16
    return (u16)(r >> 16);
}
__device__ __forceinline__ float bf2f(u16 u) {
    union { unsigned u; float f; } c; c.u = ((unsigned)u) << 16; return c.f;
}
__device__ __forceinline__ float sigmoidf_(float x) { return 1.f / (1.f + __expf(-x)); }

// async global -> LDS, 16 B per lane (wave-uniform LDS base, per-lane source)
__device__ __forceinline__ void gl_lds16(const void* g, void* l) {
    __builtin_amdgcn_global_load_lds(
        (const __attribute__((address_space(1))) unsigned int*)g,
        (__attribute__((address_space(3))) unsigned int*)l, 16, 0, 0);
}

// ---------------------------------------------------------------------------
// im2col: pixel (8,3,224,224) -> Apatch_bf (1568, 768), k = c*256 + i*16 + j
// ---------------------------------------------------------------------------
__global__ __launch_bounds__(256) void k_im2col(const float* __restrict__ px,
                                                u16* __restrict__ Ap) {
    int idx = blockIdx.x * 256 + threadIdx.x;       // 4 elems each
    if (idx >= 1568 * 192) return;
    int m = idx / 192, kq = (idx % 192) * 4;
    int b = m / NPATCH, p = m % NPATCH;
    int c = kq / 256, r = kq % 256, i = r / 16, j = r % 16;
    int y = (p / 14) * 16 + i, x = (p % 14) * 16 + j;
    float4 v = *reinterpret_cast<const float4*>(&px[((size_t)(b * 3 + c) * 224 + y) * 224 + x]);
    ushort4 w4 = { f2bf(v.x), f2bf(v.y), f2bf(v.z), f2bf(v.w) };
    *reinterpret_cast<ushort4*>(&Ap[(size_t)m * 768 + kq]) = w4;
}

// ---------------------------------------------------------------------------
// mask / argsort: brute-force stable rank per batch row (196 elems)
// ---------------------------------------------------------------------------
__global__ __launch_bounds__(256) void k_mask(const float* __restrict__ noise,
                                              int* __restrict__ ids_shuf,
                                              float* __restrict__ out_mask,
                                              float* __restrict__ out_restore) {
    __shared__ float sn[NPATCH];
    __shared__ int sshuf[NPATCH];
    int b = blockIdx.x, tid = threadIdx.x;
    if (tid < NPATCH) sn[tid] = noise[b * NPATCH + tid];
    __syncthreads();
    if (tid < NPATCH) {
        float nj = sn[tid];
        int rank = 0;
        for (int i = 0; i < NPATCH; ++i) {
            float ni = sn[i];
            rank += (ni < nj) || (ni == nj && i < tid);
        }
        out_restore[b * NPATCH + tid] = (float)rank;
        out_mask[b * NPATCH + tid] = (rank >= LEN_KEEP) ? 1.f : 0.f;
        sshuf[rank] = tid;
    }
    __syncthreads();
    if (tid < NPATCH) ids_shuf[b * NPATCH + tid] = sshuf[tid];
}

// ---------------------------------------------------------------------------
// build h: h[b,0]=cls+pos[0]; h[b,1+l]=embed[b, ids_shuf[b][l]]
// ---------------------------------------------------------------------------
__global__ __launch_bounds__(256) void k_build_h(const float* __restrict__ embed,
                                                 const int* __restrict__ ids_shuf,
                                                 const float* __restrict__ cls,
                                                 const float* __restrict__ pos,
                                                 float* __restrict__ h) {
    int blk = blockIdx.x;                // 0..1183
    int b = blk / SEQ, t = blk % SEQ, tid = threadIdx.x;
    size_t ob = (size_t)blk * DM;
    if (t == 0) {
        for (int i = tid; i < DM; i += 256) h[ob + i] = cls[i] + pos[i];
    } else {
        int j = ids_shuf[b * NPATCH + (t - 1)];
        const float* src = embed + (size_t)(b * NPATCH + j) * DM;
        for (int i = tid; i < DM; i += 256) h[ob + i] = src[i];
    }
}

// ---------------------------------------------------------------------------
// LayerNorm (eps 1e-12), 768 wide, one row per block. OUT_BF: bf16 or f32 out.
// ---------------------------------------------------------------------------
template <int OUT_BF>
__global__ __launch_bounds__(256) void k_layernorm(const float* __restrict__ in,
                                                   const float* __restrict__ w,
                                                   const float* __restrict__ b,
                                                   void* __restrict__ outv) {
    int row = blockIdx.x, tid = threadIdx.x;
    const float* x = in + (size_t)row * DM;
    float v0 = x[tid], v1 = x[tid + 256], v2 = x[tid + 512];
    float s = v0 + v1 + v2, q = v0 * v0 + v1 * v1 + v2 * v2;
#pragma unroll
    for (int off = 32; off; off >>= 1) {
        s += __shfl_down(s, off, 64);
        q += __shfl_down(q, off, 64);
    }
    __shared__ float ss[4], sq[4];
    int wid = tid >> 6, lane = tid & 63;
    if (lane == 0) { ss[wid] = s; sq[wid] = q; }
    __syncthreads();
    float st = ss[0] + ss[1] + ss[2] + ss[3];
    float qt = sq[0] + sq[1] + sq[2] + sq[3];
    float mu = st * (1.f / DM);
    float var = qt * (1.f / DM) - mu * mu;
    float rstd = rsqrtf(var + 1e-12f);
    float r0 = (v0 - mu) * rstd * w[tid]       + b[tid];
    float r1 = (v1 - mu) * rstd * w[tid + 256] + b[tid + 256];
    float r2 = (v2 - mu) * rstd * w[tid + 512] + b[tid + 512];
    if (OUT_BF) {
        u16* o = (u16*)outv + (size_t)row * DM;
        o[tid] = f2bf(r0); o[tid + 256] = f2bf(r1); o[tid + 512] = f2bf(r2);
    } else {
        float* o = (float*)outv + (size_t)row * DM;
        o[tid] = r0; o[tid + 256] = r1; o[tid + 512] = r2;
    }
}

// ---------------------------------------------------------------------------
// Pipelined bf16 NT-GEMM, BM=BN=64, BK=64, 4 waves (2x2), 2-phase dbuf.
// A: M x K bf16 (lda), B: N x K bf16 (ldb). Row-clamped loads; store-guarded.
// Swizzle: LDS holds A[row][8*(p^(row&7))] at elem row*64+p*8 (both sides).
// EPI: 1=f32 atomicAdd, 2=embed f32 (+e0[n]+e1[(1+m%196)*768+n]),
//      3=softplus(v+e0[n])->bf16, 4=bf16 store
// ---------------------------------------------------------------------------
template <int EPI>
__global__ __launch_bounds__(256) void gemm64(
    const u16* __restrict__ A, int lda, int M,
    const u16* __restrict__ B, int ldb, int N,
    void* __restrict__ Cv, int ldc, int kChunk,
    const float* __restrict__ e0, const float* __restrict__ e1) {
    __shared__ u16 sm[2][128 * 64];
    const int tid = threadIdx.x;
    const int m0 = blockIdx.x * 64, n0 = blockIdx.y * 64;
    const int kStart = blockIdx.z * kChunk;
    const int lane = tid & 63, wid = tid >> 6;
    const int wr = wid >> 1, wc = wid & 1;
    const int lr = lane & 15, lg = lane >> 4;
    const int subrow = lane >> 3, kpart = lane & 7;
    const int kel = 8 * (kpart ^ subrow);       // pre-swizzled source k-offset

    f32x4 acc[2][2] = {};
    const int nt = kChunk / 64;

    {   // prologue: stage tile 0
        const int k0 = kStart;
#pragma unroll
        for (int s = 0; s < 2; ++s) {
            int rb = wid * 16 + s * 8;
            int ra = min(m0 + rb + subrow, M - 1);
            gl_lds16(A + (size_t)ra * lda + k0 + kel, &sm[0][rb * 64]);
            int rn = min(n0 + rb + subrow, N - 1);
            gl_lds16(B + (size_t)rn * ldb + k0 + kel, &sm[0][64 * 64 + rb * 64]);
        }
    }
    __syncthreads();
    for (int t = 0; t < nt; ++t) {
        if (t + 1 < nt) {   // issue next tile's stage before compute
            const int k0 = kStart + (t + 1) * 64;
            const int buf = (t + 1) & 1;
#pragma unroll
            for (int s = 0; s < 2; ++s) {
                int rb = wid * 16 + s * 8;
                int ra = min(m0 + rb + subrow, M - 1);
                gl_lds16(A + (size_t)ra * lda + k0 + kel, &sm[buf][rb * 64]);
                int rn = min(n0 + rb + subrow, N - 1);
                gl_lds16(B + (size_t)rn * ldb + k0 + kel, &sm[buf][64 * 64 + rb * 64]);
            }
        }
        {
            const u16* sA = &sm[t & 1][0];
            const u16* sB = &sm[t & 1][64 * 64];
#pragma unroll
            for (int kk = 0; kk < 2; ++kk) {
                bf16x8 av[2], bv[2];
#pragma unroll
                for (int i = 0; i < 2; ++i) {
                    int row = wr * 32 + i * 16 + lr;
                    int e = (kk * 32 + lg * 8) ^ ((row & 7) << 3);
                    av[i] = *reinterpret_cast<const bf16x8*>(sA + row * 64 + e);
                }
#pragma unroll
                for (int j = 0; j < 2; ++j) {
                    int row = wc * 32 + j * 16 + lr;
                    int e = (kk * 32 + lg * 8) ^ ((row & 7) << 3);
                    bv[j] = *reinterpret_cast<const bf16x8*>(sB + row * 64 + e);
                }
#pragma unroll
                for (int i = 0; i < 2; ++i)
#pragma unroll
                    for (int j = 0; j < 2; ++j)
                        acc[i][j] = __builtin_amdgcn_mfma_f32_16x16x32_bf16(
                            av[i], bv[j], acc[i][j], 0, 0, 0);
            }
        }
        __syncthreads();
    }
#pragma unroll
    for (int i = 0; i < 2; ++i)
#pragma unroll
        for (int r = 0; r < 4; ++r) {
            int m = m0 + wr * 32 + i * 16 + lg * 4 + r;
            if (m >= M) continue;
#pragma unroll
            for (int j = 0; j < 2; ++j) {
                int n = n0 + wc * 32 + j * 16 + lr;
                if (n >= N) continue;
                float v = acc[i][j][r];
                size_t idx = (size_t)m * ldc + n;
                if (EPI == 1) {
                    atomicAdd((float*)Cv + idx, v);
                } else if (EPI == 2) {
                    ((float*)Cv)[idx] = v + e0[n] + e1[(size_t)(1 + (m % NPATCH)) * DM + n];
                } else if (EPI == 3) {
                    float x = v + e0[n];
                    ((u16*)Cv)[idx] = f2bf(x > 20.f ? x : log1pf(__expf(x)));
                } else {
                    ((u16*)Cv)[idx] = f2bf(v);
                }
            }
        }
}

// ---------------------------------------------------------------------------
// Causal depthwise conv(4) + silu (bf16 in/out); also zeroes xdbl (f32).
// 192 threads x 8 channels; threads 192.. zero xdbl.
// ---------------------------------------------------------------------------
__global__ __launch_bounds__(256) void k_conv(
    const u16* __restrict__ xzb,    // [1184][3072] bf16
    const float* __restrict__ cw,   // [1536][4]
    const float* __restrict__ cb,   // [1536]
    u16* __restrict__ xcb,          // [1184][1536] bf16
    float* __restrict__ xdbl) {     // [1184][80] -> zeroed
    int row = blockIdx.x, tid = threadIdx.x;
    int ti = row % SEQ;
    if (tid >= 192) {
        int t = tid - 192;
        if (t < 20)
            *reinterpret_cast<float4*>(&xdbl[(size_t)row * 80 + t * 4]) =
                make_float4(0.f, 0.f, 0.f, 0.f);
        return;
    }
    int d0 = tid * 8;
    float a[8];
#pragma unroll
    for (int e = 0; e < 8; e += 4) {
        float4 c4 = *reinterpret_cast<const float4*>(&cb[d0 + e]);
        a[e] = c4.x; a[e + 1] = c4.y; a[e + 2] = c4.z; a[e + 3] = c4.w;
    }
    float w[8][4];
#pragma unroll
    for (int e = 0; e < 8; ++e) {
        float4 c4 = *reinterpret_cast<const float4*>(&cw[(d0 + e) * 4]);
        w[e][0] = c4.x; w[e][1] = c4.y; w[e][2] = c4.z; w[e][3] = c4.w;
    }
#pragma unroll
    for (int j = 0; j < 4; ++j) {
        int tj = ti - 3 + j;
        if (tj < 0) continue;
        u16x8 xv = *reinterpret_cast<const u16x8*>(
            &xzb[(size_t)(row + tj - ti) * (2 * DI) + d0]);
#pragma unroll
        for (int e = 0; e < 8; ++e) a[e] += bf2f(xv[e]) * w[e][j];
    }
    u16x8 o;
#pragma unroll
    for (int e = 0; e < 8; ++e) { float sv = a[e] * sigmoidf_(a[e]); o[e] = f2bf(sv); }
    *reinterpret_cast<u16x8*>(&xcb[(size_t)row * DI + d0]) = o;
}

// ---------------------------------------------------------------------------
// Selective scan: 16 lanes per channel d (1 state each), sequential over L.
// ---------------------------------------------------------------------------
__global__ __launch_bounds__(256) void k_scan(
    const u16* __restrict__ dt_,    // [1184][1536] bf16 (softplus'ed)
    const u16* __restrict__ xc_,    // [1184][1536] bf16
    const float* __restrict__ xdbl, // [1184][80] f32
    const u16* __restrict__ xz_,    // [1184][3072] bf16 (z = cols 1536..)
    const float* __restrict__ A_log,// [1536][16] (layer slice)
    const float* __restrict__ Dp,   // [1536]
    u16* __restrict__ y) {          // [1184][1536] bf16
    int g = blockIdx.x * 256 + threadIdx.x;  // 196608 threads
    int n = g & 15;
    int di = g >> 4;
    int b = di / DI, d = di % DI;
    float An = -__expf(A_log[d * DST + n]);
    float Dv = Dp[d];
    float h = 0.f;
    size_t row = (size_t)b * SEQ;
    for (int t = 0; t < SEQ; ++t, ++row) {
        float dtv = bf2f(dt_[row * DI + d]);
        float xcv = bf2f(xc_[row * DI + d]);
        float Bn = xdbl[row * 80 + DTR + n];
        float Cn = xdbl[row * 80 + DTR + DST + n];
        h = __expf(dtv * An) * h + (dtv * xcv) * Bn;
        float yp = h * Cn;
        yp += __shfl_xor(yp, 1, 64);
        yp += __shfl_xor(yp, 2, 64);
        yp += __shfl_xor(yp, 4, 64);
        yp += __shfl_xor(yp, 8, 64);
        if (n == 0) {
            float zv = bf2f(xz_[row * (2 * DI) + DI + d]);
            y[row * DI + d] = f2bf((yp + xcv * Dv) * (zv * sigmoidf_(zv)));
        }
    }
}

// ---------------------------------------------------------------------------
// weight converts
// ---------------------------------------------------------------------------
__global__ __launch_bounds__(256) void k_cvt(const float* __restrict__ s,
                                             u16* __restrict__ d, int n4) {
    int i = blockIdx.x * 256 + threadIdx.x;
    if (i >= n4) return;
    float4 v = *reinterpret_cast<const float4*>(s + (size_t)i * 4);
    ushort4 w4 = { f2bf(v.x), f2bf(v.y), f2bf(v.z), f2bf(v.w) };
    *reinterpret_cast<ushort4*>(d + (size_t)i * 4) = w4;
}

#define WS0 2359296   // W_in  3072x768
#define WS1 1179648   // W_out 768x1536
#define WS2 122880    // W_x   80x1536
#define WS3 98304     // W_dt padded 1536x64 (src 1536x48)
__global__ __launch_bounds__(256) void k_cvtw(
    const float* __restrict__ Wi, const float* __restrict__ Wo,
    const float* __restrict__ Wx, const float* __restrict__ Wd,
    u16* __restrict__ oi, u16* __restrict__ oo,
    u16* __restrict__ ox, u16* __restrict__ od) {
    long i4 = ((long)blockIdx.x * 256 + threadIdx.x) * 4;
    if (i4 < WS0) {
        float4 v = *reinterpret_cast<const float4*>(Wi + i4);
        ushort4 w4 = { f2bf(v.x), f2bf(v.y), f2bf(v.z), f2bf(v.w) };
        *reinterpret_cast<ushort4*>(oi + i4) = w4;
    } else if (i4 < WS0 + WS1) {
        long j = i4 - WS0;
        float4 v = *reinterpret_cast<const float4*>(Wo + j);
        ushort4 w4 = { f2bf(v.x), f2bf(v.y), f2bf(v.z), f2bf(v.w) };
        *reinterpret_cast<ushort4*>(oo + j) = w4;
    } else if (i4 < WS0 + WS1 + WS2) {
        long j = i4 - WS0 - WS1;
        float4 v = *reinterpret_cast<const float4*>(Wx + j);
        ushort4 w4 = { f2bf(v.x), f2bf(v.y), f2bf(v.z), f2bf(v.w) };
        *reinterpret_cast<ushort4*>(ox + j) = w4;
    } else if (i4 < WS0 + WS1 + WS2 + WS3) {
        long j = i4 - WS0 - WS1 - WS2;
        int rw = (int)(j >> 6), c = (int)(j & 63);
        ushort4 w4 = { 0, 0, 0, 0 };
        if (c < DTR) {
            float4 v = *reinterpret_cast<const float4*>(Wd + (size_t)rw * DTR + c);
            w4 = { f2bf(v.x), f2bf(v.y), f2bf(v.z), f2bf(v.w) };
        }
        *reinterpret_cast<ushort4*>(od + j) = w4;
    }
}

__global__ __launch_bounds__(256) void k_cvt_xdbl(const float* __restrict__ x,
                                                  u16* __restrict__ o) {
    int i = blockIdx.x * 256 + threadIdx.x;   // MTOK*64
    if (i >= MTOK * 64) return;
    int r = i >> 6, c = i & 63;
    o[i] = (c < DTR) ? f2bf(x[r * 80 + c]) : (u16)0;
}

// ---------------------------------------------------------------------------
extern "C" void kernel_launch(void* const* d_in, const int* in_sizes, int n_in,
                              void* d_out, int out_size, void* d_ws, size_t ws_size,
                              hipStream_t stream) {
    const float* pixel  = (const float*)d_in[0];
    const float* noise  = (const float*)d_in[1];
    const float* conv_w = (const float*)d_in[2];
    const float* conv_b = (const float*)d_in[3];
    const float* cls    = (const float*)d_in[4];
    const float* pos    = (const float*)d_in[5];
    const float* ln_w   = (const float*)d_in[6];
    const float* ln_b   = (const float*)d_in[7];
    const float* W_in   = (const float*)d_in[8];
    const float* c1w    = (const float*)d_in[9];
    const float* c1b    = (const float*)d_in[10];
    const float* W_x    = (const float*)d_in[11];
    const float* W_dt   = (const float*)d_in[12];
    const float* dtb    = (const float*)d_in[13];
    const float* A_log  = (const float*)d_in[14];
    const float* Dp     = (const float*)d_in[15];
    const float* W_out  = (const float*)d_in[16];
    const float* lnf_w  = (const float*)d_in[17];
    const float* lnf_b  = (const float*)d_in[18];

    float* out = (float*)d_out;
    float* h = out;                                   // [1184][768] f32
    float* out_mask    = out + MTOK * DM;
    float* out_restore = out + MTOK * DM + BATCH * NPATCH;

    // ---- workspace layout (byte offsets, 16B-aligned) ----
    char* wsb = (char*)d_ws;
    u16*  xz_bf   = (u16*)(wsb + 0);          // 1184x3072x2 = 7,274,496
    u16*  xln_bf  = (u16*)(wsb + 7274496);    // 1,818,624
    u16*  xc_bf   = (u16*)(wsb + 9093120);    // 3,637,248
    u16*  dt_bf   = (u16*)(wsb + 12730368);   // 3,637,248
    u16*  yb_bf   = (u16*)(wsb + 16367616);   // 3,637,248
    float* xdbl   = (float*)(wsb + 20004864); // 1184x80x4 = 378,880
    u16*  xdbl_bf = (u16*)(wsb + 20383744);   // 1184x64x2 = 151,552
    u16*  apatch  = (u16*)(wsb + 20535296);   // 1568x768x2 = 2,408,448
    float* embed  = (float*)(wsb + 22943744); // 1568x768x4 = 4,816,896
    int*  ids     = (int*)(wsb + 27760640);   // 6,272
    u16*  cw_bf   = (u16*)(wsb + 27766912);   // 1,179,648
    u16*  wi_bf   = (u16*)(wsb + 28946560);   // WS0*2
    u16*  wo_bf   = wi_bf + WS0;
    u16*  wx_bf   = wo_bf + WS1;
    u16*  wd_bf   = wx_bf + WS2;              // total end ~36.5 MB

    // ---- setup ----
    k_im2col<<<1176, 256, 0, stream>>>(pixel, apatch);
    k_mask<<<BATCH, 256, 0, stream>>>(noise, ids, out_mask, out_restore);
    k_cvt<<<576, 256, 0, stream>>>(conv_w, cw_bf, 147456);
    gemm64<2><<<dim3(25, 12, 1), 256, 0, stream>>>(
        apatch, 768, 1568, cw_bf, 768, 768, embed, DM, 768, conv_b, pos);
    k_build_h<<<MTOK, 256, 0, stream>>>(embed, ids, cls, pos, h);

    // ---- layers ----
    for (int l = 0; l < 12; ++l) {
        k_cvtw<<<3672, 256, 0, stream>>>(
            W_in + (size_t)l * WS0, W_out + (size_t)l * WS1,
            W_x + (size_t)l * WS2, W_dt + (size_t)l * DI * DTR,
            wi_bf, wo_bf, wx_bf, wd_bf);
        k_layernorm<1><<<MTOK, 256, 0, stream>>>(h, ln_w + l * DM, ln_b + l * DM, xln_bf);
        // xz = xln @ W_in^T -> bf16
        gemm64<4><<<dim3(19, 48, 1), 256, 0, stream>>>(
            xln_bf, DM, MTOK, wi_bf, DM, 2 * DI, xz_bf, 2 * DI, DM, nullptr, nullptr);
        // conv+silu -> xc_bf; zero xdbl
        k_conv<<<MTOK, 256, 0, stream>>>(xz_bf, c1w + l * DI * 4, c1b + l * DI, xc_bf, xdbl);
        // xdbl += xc @ W_x^T (split-K 8 x 192)
        gemm64<1><<<dim3(19, 2, 8), 256, 0, stream>>>(
            xc_bf, DI, MTOK, wx_bf, DI, 80, xdbl, 80, 192, nullptr, nullptr);
        k_cvt_xdbl<<<296, 256, 0, stream>>>(xdbl, xdbl_bf);
        // dt = softplus(xdbl[:, :48] @ W_dt^T + dtb) -> bf16   (K padded to 64)
        gemm64<3><<<dim3(19, 24, 1), 256, 0, stream>>>(
            xdbl_bf, 64, MTOK, wd_bf, 64, DI, dt_bf, DI, 64, dtb + l * DI, nullptr);
        k_scan<<<768, 256, 0, stream>>>(dt_bf, xc_bf, xdbl, xz_bf,
                                        A_log + (size_t)l * DI * DST, Dp + l * DI, yb_bf);
        // h += yb @ W_out^T (split-K 2 x 768, atomicAdd into residual)
        gemm64<1><<<dim3(19, 12, 2), 256, 0, stream>>>(
            yb_bf, DI, MTOK, wo_bf, DI, DM, h, DM, 768, nullptr, nullptr);
    }
    k_layernorm<0><<<MTOK, 256, 0, stream>>>(h, lnf_w, lnf_b, h);
}

// Round 4
// 1567.610 us; speedup vs baseline: 3.4970x; 1.5496x over previous
//
#include <hip/hip_runtime.h>

// ---------------------------------------------------------------------------
// PIXBA (Mamba vision encoder + MAE masking) forward, MI355X gfx950.
// Round 4: transposed (channel-major) dataflow for conv/scan -> vectorized
// time-axis loads; scan 8-step chunks; conv dual-layout output via LDS.
// ---------------------------------------------------------------------------

#define BATCH 8
#define NPATCH 196
#define LEN_KEEP 147
#define SEQ 148            // 1 + LEN_KEEP
#define DM 768
#define DI 1536
#define DTR 48
#define DST 16
#define MTOK (BATCH*SEQ)   // 1184
#define MT MTOK

typedef __bf16 bf16_t;
typedef bf16_t bf16x8 __attribute__((ext_vector_type(8)));
typedef float  f32x4  __attribute__((ext_vector_type(4)));
typedef unsigned short u16;
typedef u16 u16x8 __attribute__((ext_vector_type(8)));

__device__ __forceinline__ u16 f2bf(float f) {
    union { float f; unsigned u; } c; c.f = f;
    unsigned r = c.u + 0x7FFFu + ((c.u >> 16) & 1u);   // RNE to bf16
    return (u16)(r >> 16);
}
__device__ __forceinline__ float bf2f(u16 u) {
    union { unsigned u; float f; } c; c.u = ((unsigned)u) << 16; return c.f;
}
__device__ __forceinline__ float sigmoidf_(float x) { return 1.f / (1.f + __expf(-x)); }

// async global -> LDS, 16 B per lane (wave-uniform LDS base, per-lane source)
__device__ __forceinline__ void gl_lds16(const void* g, void* l) {
    __builtin_amdgcn_global_load_lds(
        (const __attribute__((address_space(1))) unsigned int*)g,
        (__attribute__((address_space(3))) unsigned int*)l, 16, 0, 0);
}

// ---------------------------------------------------------------------------
// im2col: pixel (8,3,224,224) -> Apatch_bf (1568, 768), k = c*256 + i*16 + j
// ---------------------------------------------------------------------------
__global__ __launch_bounds__(256) void k_im2col(const float* __restrict__ px,
                                                u16* __restrict__ Ap) {
    int idx = blockIdx.x * 256 + threadIdx.x;       // 4 elems each
    if (idx >= 1568 * 192) return;
    int m = idx / 192, kq = (idx % 192) * 4;
    int b = m / NPATCH, p = m % NPATCH;
    int c = kq / 256, r = kq % 256, i = r / 16, j = r % 16;
    int y = (p / 14) * 16 + i, x = (p % 14) * 16 + j;
    float4 v = *reinterpret_cast<const float4*>(&px[((size_t)(b * 3 + c) * 224 + y) * 224 + x]);
    ushort4 w4 = { f2bf(v.x), f2bf(v.y), f2bf(v.z), f2bf(v.w) };
    *reinterpret_cast<ushort4*>(&Ap[(size_t)m * 768 + kq]) = w4;
}

// ---------------------------------------------------------------------------
// mask / argsort: brute-force stable rank per batch row (196 elems)
// ---------------------------------------------------------------------------
__global__ __launch_bounds__(256) void k_mask(const float* __restrict__ noise,
                                              int* __restrict__ ids_shuf,
                                              float* __restrict__ out_mask,
                                              float* __restrict__ out_restore) {
    __shared__ float sn[NPATCH];
    __shared__ int sshuf[NPATCH];
    int b = blockIdx.x, tid = threadIdx.x;
    if (tid < NPATCH) sn[tid] = noise[b * NPATCH + tid];
    __syncthreads();
    if (tid < NPATCH) {
        float nj = sn[tid];
        int rank = 0;
        for (int i = 0; i < NPATCH; ++i) {
            float ni = sn[i];
            rank += (ni < nj) || (ni == nj && i < tid);
        }
        out_restore[b * NPATCH + tid] = (float)rank;
        out_mask[b * NPATCH + tid] = (rank >= LEN_KEEP) ? 1.f : 0.f;
        sshuf[rank] = tid;
    }
    __syncthreads();
    if (tid < NPATCH) ids_shuf[b * NPATCH + tid] = sshuf[tid];
}

// ---------------------------------------------------------------------------
// build h: h[b,0]=cls+pos[0]; h[b,1+l]=embed[b, ids_shuf[b][l]]
// ---------------------------------------------------------------------------
__global__ __launch_bounds__(256) void k_build_h(const float* __restrict__ embed,
                                                 const int* __restrict__ ids_shuf,
                                                 const float* __restrict__ cls,
                                                 const float* __restrict__ pos,
                                                 float* __restrict__ h) {
    int blk = blockIdx.x;                // 0..1183
    int b = blk / SEQ, t = blk % SEQ, tid = threadIdx.x;
    size_t ob = (size_t)blk * DM;
    if (t == 0) {
        for (int i = tid; i < DM; i += 256) h[ob + i] = cls[i] + pos[i];
    } else {
        int j = ids_shuf[b * NPATCH + (t - 1)];
        const float* src = embed + (size_t)(b * NPATCH + j) * DM;
        for (int i = tid; i < DM; i += 256) h[ob + i] = src[i];
    }
}

// ---------------------------------------------------------------------------
// LayerNorm (eps 1e-12), 768 wide, one row per block. OUT_BF: bf16 or f32 out.
// ---------------------------------------------------------------------------
template <int OUT_BF>
__global__ __launch_bounds__(256) void k_layernorm(const float* __restrict__ in,
                                                   const float* __restrict__ w,
                                                   const float* __restrict__ b,
                                                   void* __restrict__ outv) {
    int row = blockIdx.x, tid = threadIdx.x;
    const float* x = in + (size_t)row * DM;
    float v0 = x[tid], v1 = x[tid + 256], v2 = x[tid + 512];
    float s = v0 + v1 + v2, q = v0 * v0 + v1 * v1 + v2 * v2;
#pragma unroll
    for (int off = 32; off; off >>= 1) {
        s += __shfl_down(s, off, 64);
        q += __shfl_down(q, off, 64);
    }
    __shared__ float ss[4], sq[4];
    int wid = tid >> 6, lane = tid & 63;
    if (lane == 0) { ss[wid] = s; sq[wid] = q; }
    __syncthreads();
    float st = ss[0] + ss[1] + ss[2] + ss[3];
    float qt = sq[0] + sq[1] + sq[2] + sq[3];
    float mu = st * (1.f / DM);
    float var = qt * (1.f / DM) - mu * mu;
    float rstd = rsqrtf(var + 1e-12f);
    float r0 = (v0 - mu) * rstd * w[tid]       + b[tid];
    float r1 = (v1 - mu) * rstd * w[tid + 256] + b[tid + 256];
    float r2 = (v2 - mu) * rstd * w[tid + 512] + b[tid + 512];
    if (OUT_BF) {
        u16* o = (u16*)outv + (size_t)row * DM;
        o[tid] = f2bf(r0); o[tid + 256] = f2bf(r1); o[tid + 512] = f2bf(r2);
    } else {
        float* o = (float*)outv + (size_t)row * DM;
        o[tid] = r0; o[tid + 256] = r1; o[tid + 512] = r2;
    }
}

// ---------------------------------------------------------------------------
// Pipelined bf16 NT-GEMM, BM=BN=64, BK=64, 4 waves (2x2), 2-phase dbuf.
// A: M x K bf16 (lda), B: N x K bf16 (ldb). Row-clamped loads; store-guarded.
// Swizzle: LDS elem [row][8*p] holds global k 8*(p^(row&7)) (both sides agree).
// EPI: 1=f32 atomicAdd, 2=embed f32 (+e0[n]+e1[(1+m%196)*768+n]),
//      3=softplus(v+e0[n])->bf16, 4=bf16 store, 5=softplus(v+e0[m])->bf16
// ---------------------------------------------------------------------------
template <int EPI>
__global__ __launch_bounds__(256) void gemm64(
    const u16* __restrict__ A, int lda, int M,
    const u16* __restrict__ B, int ldb, int N,
    void* __restrict__ Cv, int ldc, int kChunk,
    const float* __restrict__ e0, const float* __restrict__ e1) {
    __shared__ u16 sm[2][128 * 64];
    const int tid = threadIdx.x;
    const int m0 = blockIdx.x * 64, n0 = blockIdx.y * 64;
    const int kStart = blockIdx.z * kChunk;
    const int lane = tid & 63, wid = tid >> 6;
    const int wr = wid >> 1, wc = wid & 1;
    const int lr = lane & 15, lg = lane >> 4;
    const int subrow = lane >> 3, kpart = lane & 7;
    const int kel = 8 * (kpart ^ subrow);       // pre-swizzled source k-offset

    f32x4 acc[2][2] = {};
    const int nt = kChunk / 64;

    {   // prologue: stage tile 0
        const int k0 = kStart;
#pragma unroll
        for (int s = 0; s < 2; ++s) {
            int rb = wid * 16 + s * 8;
            int ra = min(m0 + rb + subrow, M - 1);
            gl_lds16(A + (size_t)ra * lda + k0 + kel, &sm[0][rb * 64]);
            int rn = min(n0 + rb + subrow, N - 1);
            gl_lds16(B + (size_t)rn * ldb + k0 + kel, &sm[0][64 * 64 + rb * 64]);
        }
    }
    __syncthreads();
    for (int t = 0; t < nt; ++t) {
        if (t + 1 < nt) {   // issue next tile's stage before compute
            const int k0 = kStart + (t + 1) * 64;
            const int buf = (t + 1) & 1;
#pragma unroll
            for (int s = 0; s < 2; ++s) {
                int rb = wid * 16 + s * 8;
                int ra = min(m0 + rb + subrow, M - 1);
                gl_lds16(A + (size_t)ra * lda + k0 + kel, &sm[buf][rb * 64]);
                int rn = min(n0 + rb + subrow, N - 1);
                gl_lds16(B + (size_t)rn * ldb + k0 + kel, &sm[buf][64 * 64 + rb * 64]);
            }
        }
        {
            const u16* sA = &sm[t & 1][0];
            const u16* sB = &sm[t & 1][64 * 64];
#pragma unroll
            for (int kk = 0; kk < 2; ++kk) {
                bf16x8 av[2], bv[2];
#pragma unroll
                for (int i = 0; i < 2; ++i) {
                    int row = wr * 32 + i * 16 + lr;
                    int e = (kk * 32 + lg * 8) ^ ((row & 7) << 3);
                    av[i] = *reinterpret_cast<const bf16x8*>(sA + row * 64 + e);
                }
#pragma unroll
                for (int j = 0; j < 2; ++j) {
                    int row = wc * 32 + j * 16 + lr;
                    int e = (kk * 32 + lg * 8) ^ ((row & 7) << 3);
                    bv[j] = *reinterpret_cast<const bf16x8*>(sB + row * 64 + e);
                }
#pragma unroll
                for (int i = 0; i < 2; ++i)
#pragma unroll
                    for (int j = 0; j < 2; ++j)
                        acc[i][j] = __builtin_amdgcn_mfma_f32_16x16x32_bf16(
                            av[i], bv[j], acc[i][j], 0, 0, 0);
            }
        }
        __syncthreads();
    }
#pragma unroll
    for (int i = 0; i < 2; ++i)
#pragma unroll
        for (int r = 0; r < 4; ++r) {
            int m = m0 + wr * 32 + i * 16 + lg * 4 + r;
            if (m >= M) continue;
#pragma unroll
            for (int j = 0; j < 2; ++j) {
                int n = n0 + wc * 32 + j * 16 + lr;
                if (n >= N) continue;
                float v = acc[i][j][r];
                size_t idx = (size_t)m * ldc + n;
                if (EPI == 1) {
                    atomicAdd((float*)Cv + idx, v);
                } else if (EPI == 2) {
                    ((float*)Cv)[idx] = v + e0[n] + e1[(size_t)(1 + (m % NPATCH)) * DM + n];
                } else if (EPI == 3) {
                    float x = v + e0[n];
                    ((u16*)Cv)[idx] = f2bf(x > 20.f ? x : log1pf(__expf(x)));
                } else if (EPI == 4) {
                    ((u16*)Cv)[idx] = f2bf(v);
                } else {  // 5: softplus with row (m) bias -> bf16
                    float x = v + e0[m];
                    ((u16*)Cv)[idx] = f2bf(x > 20.f ? x : log1pf(__expf(x)));
                }
            }
        }
}

// ---------------------------------------------------------------------------
// Causal depthwise conv(4)+silu on channel-major xs^T.
// Block = (64-channel tile, batch). Threads: dl = tid&63 (channel),
// tc = tid>>6 (t-chunk of 37). Outputs xc^T AND token-major xc via LDS.
// Also zeroes xdbl (blocks with blockIdx.x==0).
// ---------------------------------------------------------------------------
template <int TC>
__device__ __forceinline__ void conv_piece(const u16* __restrict__ xrow,
                                           const float w0, const float w1,
                                           const float w2, const float w3,
                                           const float cbv,
                                           u16* __restrict__ sout) {
    constexpr int START = (TC == 0) ? 0 : (TC == 1) ? 32 : (TC == 2) ? 64 : 104;
    u16x8 buf[6];
#pragma unroll
    for (int i = 0; i < 6; ++i)
        buf[i] = *reinterpret_cast<const u16x8*>(xrow + START + 8 * i);
    const float wj[4] = { w0, w1, w2, w3 };
#pragma unroll
    for (int i = 0; i < 37; ++i) {
        const int t = TC * 37 + i;
        float acc = cbv;
#pragma unroll
        for (int j = 0; j < 4; ++j) {
            const int q = t - 3 + j;
            if (TC == 0 && q < 0) continue;      // folds at compile time
            const int idx = q - START;
            acc += bf2f(buf[idx >> 3][idx & 7]) * wj[j];
        }
        acc = acc * sigmoidf_(acc);
        sout[t] = f2bf(acc);
    }
}

__global__ __launch_bounds__(256) void k_conv(
    const u16* __restrict__ xzT,    // [3072][1184] (xs = rows 0..1535)
    const float* __restrict__ cw,   // [1536][4]
    const float* __restrict__ cb,   // [1536]
    u16* __restrict__ xcT,          // [1536][1184]
    u16* __restrict__ xcTok,        // [1184][1536]
    float* __restrict__ xdbl) {     // [1184][80] -> zeroed
    __shared__ u16 sxc[64][152];
    const int tid = threadIdx.x;
    const int d0 = blockIdx.x * 64, b = blockIdx.y;
    const int dl = tid & 63, tc = tid >> 6;
    const int d = d0 + dl;
    float4 w4 = *reinterpret_cast<const float4*>(&cw[d * 4]);
    float cbv = cb[d];
    const u16* xrow = xzT + (size_t)d * MT + b * SEQ;
    switch (tc) {
        case 0: conv_piece<0>(xrow, w4.x, w4.y, w4.z, w4.w, cbv, &sxc[dl][0]); break;
        case 1: conv_piece<1>(xrow, w4.x, w4.y, w4.z, w4.w, cbv, &sxc[dl][0]); break;
        case 2: conv_piece<2>(xrow, w4.x, w4.y, w4.z, w4.w, cbv, &sxc[dl][0]); break;
        default: conv_piece<3>(xrow, w4.x, w4.y, w4.z, w4.w, cbv, &sxc[dl][0]); break;
    }
    if (blockIdx.x == 0) {          // zero xdbl slice for this batch
        float4* xo = reinterpret_cast<float4*>(xdbl + (size_t)b * SEQ * 80);
        for (int c = tid; c < SEQ * 20; c += 256) xo[c] = make_float4(0.f, 0.f, 0.f, 0.f);
    }
    __syncthreads();
    // phase 1: xc^T rows (18 x u16x8 + 1 x ushort4 per row)
    for (int c = tid; c < 64 * 19; c += 256) {
        int dd = c / 19, ch = c % 19;
        size_t gbase = (size_t)(d0 + dd) * MT + b * SEQ;
        if (ch < 18)
            *reinterpret_cast<u16x8*>(&xcT[gbase + ch * 8]) =
                *reinterpret_cast<const u16x8*>(&sxc[dd][ch * 8]);
        else
            *reinterpret_cast<ushort4*>(&xcT[gbase + 144]) =
                *reinterpret_cast<const ushort4*>(&sxc[dd][144]);
    }
    // phase 2: token-major
    if (tid < SEQ) {
        int t = tid;
        size_t gb = (size_t)(b * SEQ + t) * DI + d0;
#pragma unroll
        for (int g = 0; g < 8; ++g) {
            u16x8 v;
#pragma unroll
            for (int e = 0; e < 8; ++e) v[e] = sxc[g * 8 + e][t];
            *reinterpret_cast<u16x8*>(&xcTok[gb + g * 8]) = v;
        }
    }
}

// ---------------------------------------------------------------------------
// Selective scan v3: 16 lanes per (b,d); 8-step chunks with vector loads from
// channel-major dt^T/xc^T/z^T and xdblT; y LDS-transposed to token-major.
// Grid (96, 8): blockIdx.x = 16-channel tile, blockIdx.y = batch.
// ---------------------------------------------------------------------------
__global__ __launch_bounds__(256) void k_scan(
    const u16* __restrict__ dtT,    // [1536][1184] bf16
    const u16* __restrict__ xcT,    // [1536][1184] bf16
    const u16* __restrict__ xzT,    // [3072][1184] bf16 (z = rows 1536..)
    const float* __restrict__ xdT,  // [32][1184] f32: rows 0..15 = B, 16..31 = C
    const float* __restrict__ A_log,// [1536][16] (layer slice)
    const float* __restrict__ Dp,   // [1536]
    u16* __restrict__ y) {          // [1184][1536] bf16 token-major
    __shared__ u16 sy[16][152];
    const int tid = threadIdx.x;
    const int d0 = blockIdx.x * 16, b = blockIdx.y;
    const int dl = tid >> 4, n = tid & 15;
    const int d = d0 + dl;
    const float An = -__expf(A_log[d * DST + n]);
    const float Dv = Dp[d];
    const u16* dtrow = dtT + (size_t)d * MT + b * SEQ;
    const u16* xcrow = xcT + (size_t)d * MT + b * SEQ;
    const u16* zrow  = xzT + (size_t)(DI + d) * MT + b * SEQ;
    const float* Brow = xdT + (size_t)n * MT + b * SEQ;
    const float* Crow = xdT + (size_t)(16 + n) * MT + b * SEQ;
    float h = 0.f;
    for (int t0 = 0; t0 < SEQ; t0 += 8) {
        u16x8 dt8 = *reinterpret_cast<const u16x8*>(dtrow + t0);
        u16x8 xc8 = *reinterpret_cast<const u16x8*>(xcrow + t0);
        u16x8 z8  = *reinterpret_cast<const u16x8*>(zrow + t0);
        float4 B0 = *reinterpret_cast<const float4*>(Brow + t0);
        float4 B1 = *reinterpret_cast<const float4*>(Brow + t0 + 4);
        float4 C0 = *reinterpret_cast<const float4*>(Crow + t0);
        float4 C1 = *reinterpret_cast<const float4*>(Crow + t0 + 4);
        const float Ba[8] = { B0.x, B0.y, B0.z, B0.w, B1.x, B1.y, B1.z, B1.w };
        const float Ca[8] = { C0.x, C0.y, C0.z, C0.w, C1.x, C1.y, C1.z, C1.w };
#pragma unroll
        for (int j = 0; j < 8; ++j) {
            if (t0 + j < SEQ) {
                float dtv = bf2f(dt8[j]);
                float xcv = bf2f(xc8[j]);
                float e = __expf(dtv * An);
                h = e * h + (dtv * xcv) * Ba[j];
                float yp = h * Ca[j];
                yp += __shfl_xor(yp, 1, 64);
                yp += __shfl_xor(yp, 2, 64);
                yp += __shfl_xor(yp, 4, 64);
                yp += __shfl_xor(yp, 8, 64);
                if (n == 0) {
                    float zv = bf2f(z8[j]);
                    sy[dl][t0 + j] = f2bf((yp + xcv * Dv) * (zv * sigmoidf_(zv)));
                }
            }
        }
    }
    __syncthreads();
    if (tid < SEQ) {
        int t = tid;
        size_t gb = (size_t)(b * SEQ + t) * DI + d0;
#pragma unroll
        for (int g = 0; g < 2; ++g) {
            u16x8 v;
#pragma unroll
            for (int e = 0; e < 8; ++e) v[e] = sy[g * 8 + e][t];
            *reinterpret_cast<u16x8*>(&y[gb + g * 8]) = v;
        }
    }
}

// ---------------------------------------------------------------------------
// weight converts
// ---------------------------------------------------------------------------
__global__ __launch_bounds__(256) void k_cvt(const float* __restrict__ s,
                                             u16* __restrict__ d, int n4) {
    int i = blockIdx.x * 256 + threadIdx.x;
    if (i >= n4) return;
    float4 v = *reinterpret_cast<const float4*>(s + (size_t)i * 4);
    ushort4 w4 = { f2bf(v.x), f2bf(v.y), f2bf(v.z), f2bf(v.w) };
    *reinterpret_cast<ushort4*>(d + (size_t)i * 4) = w4;
}

#define WS0 2359296   // W_in  3072x768
#define WS1 1179648   // W_out 768x1536
#define WS2 122880    // W_x   80x1536
#define WS3 98304     // W_dt padded 1536x64 (src 1536x48)
__global__ __launch_bounds__(256) void k_cvtw(
    const float* __restrict__ Wi, const float* __restrict__ Wo,
    const float* __restrict__ Wx, const float* __restrict__ Wd,
    u16* __restrict__ oi, u16* __restrict__ oo,
    u16* __restrict__ ox, u16* __restrict__ od) {
    long i4 = ((long)blockIdx.x * 256 + threadIdx.x) * 4;
    if (i4 < WS0) {
        float4 v = *reinterpret_cast<const float4*>(Wi + i4);
        ushort4 w4 = { f2bf(v.x), f2bf(v.y), f2bf(v.z), f2bf(v.w) };
        *reinterpret_cast<ushort4*>(oi + i4) = w4;
    } else if (i4 < WS0 + WS1) {
        long j = i4 - WS0;
        float4 v = *reinterpret_cast<const float4*>(Wo + j);
        ushort4 w4 = { f2bf(v.x), f2bf(v.y), f2bf(v.z), f2bf(v.w) };
        *reinterpret_cast<ushort4*>(oo + j) = w4;
    } else if (i4 < WS0 + WS1 + WS2) {
        long j = i4 - WS0 - WS1;
        float4 v = *reinterpret_cast<const float4*>(Wx + j);
        ushort4 w4 = { f2bf(v.x), f2bf(v.y), f2bf(v.z), f2bf(v.w) };
        *reinterpret_cast<ushort4*>(ox + j) = w4;
    } else if (i4 < WS0 + WS1 + WS2 + WS3) {
        long j = i4 - WS0 - WS1 - WS2;
        int rw = (int)(j >> 6), c = (int)(j & 63);
        ushort4 w4 = { 0, 0, 0, 0 };
        if (c < DTR) {
            float4 v = *reinterpret_cast<const float4*>(Wd + (size_t)rw * DTR + c);
            w4 = { f2bf(v.x), f2bf(v.y), f2bf(v.z), f2bf(v.w) };
        }
        *reinterpret_cast<ushort4*>(od + j) = w4;
    }
}

// xdbl [1184][80] f32 -> xdbl_bf [1184][64] bf16 (cols 0..47, zero-pad)
//                     -> xdT [32][1184] f32 (rows = cols 48..79 transposed)
__global__ __launch_bounds__(256) void k_cvt_xdbl(const float* __restrict__ x,
                                                  u16* __restrict__ obf,
                                                  float* __restrict__ oT) {
    int i = blockIdx.x * 256 + threadIdx.x;      // 75776 + 37888 = 113664
    if (i < MTOK * 64) {
        int r = i >> 6, c = i & 63;
        obf[i] = (c < DTR) ? f2bf(x[(size_t)r * 80 + c]) : (u16)0;
    } else {
        int j = i - MTOK * 64;
        if (j < 32 * MTOK) {
            int rr = j / MTOK, m = j - rr * MTOK;
            oT[(size_t)rr * MTOK + m] = x[(size_t)m * 80 + 48 + rr];
        }
    }
}

// ---------------------------------------------------------------------------
extern "C" void kernel_launch(void* const* d_in, const int* in_sizes, int n_in,
                              void* d_out, int out_size, void* d_ws, size_t ws_size,
                              hipStream_t stream) {
    const float* pixel  = (const float*)d_in[0];
    const float* noise  = (const float*)d_in[1];
    const float* conv_w = (const float*)d_in[2];
    const float* conv_b = (const float*)d_in[3];
    const float* cls    = (const float*)d_in[4];
    const float* pos    = (const float*)d_in[5];
    const float* ln_w   = (const float*)d_in[6];
    const float* ln_b   = (const float*)d_in[7];
    const float* W_in   = (const float*)d_in[8];
    const float* c1w    = (const float*)d_in[9];
    const float* c1b    = (const float*)d_in[10];
    const float* W_x    = (const float*)d_in[11];
    const float* W_dt   = (const float*)d_in[12];
    const float* dtb    = (const float*)d_in[13];
    const float* A_log  = (const float*)d_in[14];
    const float* Dp     = (const float*)d_in[15];
    const float* W_out  = (const float*)d_in[16];
    const float* lnf_w  = (const float*)d_in[17];
    const float* lnf_b  = (const float*)d_in[18];

    float* out = (float*)d_out;
    float* h = out;                                   // [1184][768] f32
    float* out_mask    = out + MTOK * DM;
    float* out_restore = out + MTOK * DM + BATCH * NPATCH;

    // ---- workspace layout (byte offsets, 64-aligned, tail-padded) ----
    char* wsb = (char*)d_ws;
    u16*  xzT     = (u16*)(wsb + 0);          // 3072x1184x2 = 7,274,496 (+64)
    u16*  xcT     = (u16*)(wsb + 7274560);    // 1536x1184x2 = 3,637,248 (+64)
    u16*  xcTok   = (u16*)(wsb + 10911872);   // 1184x1536x2 = 3,637,248
    u16*  dtT     = (u16*)(wsb + 14549120);   // 1536x1184x2 = 3,637,248 (+64)
    u16*  yb      = (u16*)(wsb + 18186432);   // 1184x1536x2 = 3,637,248
    u16*  xln_bf  = (u16*)(wsb + 21823680);   // 1,818,624
    float* xdbl   = (float*)(wsb + 23642304); // 1184x80x4 = 378,880
    u16*  xdbl_bf = (u16*)(wsb + 24021184);   // 1184x64x2 = 151,552
    float* xdT    = (float*)(wsb + 24172736); // 32x1184x4 = 151,552 (+64)
    u16*  apatch  = (u16*)(wsb + 24324352);   // 1568x768x2 = 2,408,448
    float* embed  = (float*)(wsb + 26732800); // 1568x768x4 = 4,816,896
    int*  ids     = (int*)(wsb + 31549696);   // 6,272
    u16*  cw_bf   = (u16*)(wsb + 31555968);   // 1,179,648
    u16*  wi_bf   = (u16*)(wsb + 32735616);   // 4,718,592
    u16*  wo_bf   = wi_bf + WS0;
    u16*  wx_bf   = wo_bf + WS1;
    u16*  wd_bf   = wx_bf + WS2;              // end ~40.3 MB

    // ---- setup ----
    k_im2col<<<1176, 256, 0, stream>>>(pixel, apatch);
    k_mask<<<BATCH, 256, 0, stream>>>(noise, ids, out_mask, out_restore);
    k_cvt<<<576, 256, 0, stream>>>(conv_w, cw_bf, 147456);
    gemm64<2><<<dim3(25, 12, 1), 256, 0, stream>>>(
        apatch, 768, 1568, cw_bf, 768, 768, embed, DM, 768, conv_b, pos);
    k_build_h<<<MTOK, 256, 0, stream>>>(embed, ids, cls, pos, h);

    // ---- layers ----
    for (int l = 0; l < 12; ++l) {
        k_cvtw<<<3672, 256, 0, stream>>>(
            W_in + (size_t)l * WS0, W_out + (size_t)l * WS1,
            W_x + (size_t)l * WS2, W_dt + (size_t)l * DI * DTR,
            wi_bf, wo_bf, wx_bf, wd_bf);
        k_layernorm<1><<<MTOK, 256, 0, stream>>>(h, ln_w + l * DM, ln_b + l * DM, xln_bf);
        // xz^T = (W_in @ xln^T): A=W_in rows (3072), B=xln rows (1184)
        gemm64<4><<<dim3(48, 19, 1), 256, 0, stream>>>(
            wi_bf, DM, 3072, xln_bf, DM, MTOK, xzT, MT, DM, nullptr, nullptr);
        // conv+silu -> xc^T and token-major xc; zero xdbl
        k_conv<<<dim3(24, 8), 256, 0, stream>>>(
            xzT, c1w + l * DI * 4, c1b + l * DI, xcT, xcTok, xdbl);
        // xdbl += xc @ W_x^T (split-K 8 x 192), token-major
        gemm64<1><<<dim3(19, 2, 8), 256, 0, stream>>>(
            xcTok, DI, MTOK, wx_bf, DI, 80, xdbl, 80, 192, nullptr, nullptr);
        k_cvt_xdbl<<<444, 256, 0, stream>>>(xdbl, xdbl_bf, xdT);
        // dt^T = softplus(W_dt @ xdbl^T + dtb[m]): A=W_dt rows (1536 ch)
        gemm64<5><<<dim3(24, 19, 1), 256, 0, stream>>>(
            wd_bf, 64, DI, xdbl_bf, 64, MTOK, dtT, MT, 64, dtb + l * DI, nullptr);
        k_scan<<<dim3(96, 8), 256, 0, stream>>>(
            dtT, xcT, xzT, xdT, A_log + (size_t)l * DI * DST, Dp + l * DI, yb);
        // h += y @ W_out^T (split-K 2 x 768, atomicAdd into residual)
        gemm64<1><<<dim3(19, 12, 2), 256, 0, stream>>>(
            yb, DI, MTOK, wo_bf, DI, DM, h, DM, 768, nullptr, nullptr);
    }
    k_layernorm<0><<<MTOK, 256, 0, stream>>>(h, lnf_w, lnf_b, h);
}